// Round 1
// baseline (785.924 us; speedup 1.0000x reference)
//
#include <hip/hip_runtime.h>
#include <hip/hip_bf16.h>
#include <math.h>

typedef __attribute__((ext_vector_type(8))) short short8;
typedef __attribute__((ext_vector_type(4))) float f32x4;

#define NB 4
#define NS 2048
#define ND 1024
#define NH 16
#define NDK 64
#define NF 4096
#define NM (NB*NS)   // 8192 rows total

__device__ __forceinline__ unsigned short f2b(float f) {
  union { __hip_bfloat16 h; unsigned short u; } c;
  c.h = __float2bfloat16(f);
  return c.u;
}

__device__ __forceinline__ void gload_lds16(const void* g, void* l) {
  __builtin_amdgcn_global_load_lds((const __attribute__((address_space(1))) void*)g,
                                   (__attribute__((address_space(3))) void*)l,
                                   16, 0, 0);
}

// ---------------- conversions / weight prep ----------------

__global__ __launch_bounds__(256)
void cvt_f32_bf16(const float* __restrict__ in, unsigned short* __restrict__ out, int n4) {
  int i = blockIdx.x * 256 + threadIdx.x;
  if (i >= n4) return;
  float4 v = ((const float4*)in)[i];
  ushort4 o;
  o.x = f2b(v.x); o.y = f2b(v.y); o.z = f2b(v.z); o.w = f2b(v.w);
  ((ushort4*)out)[i] = o;
}

// src: fp32 [K][N] (row stride ldsrc); dst: bf16 [N][K] (row stride lddst)
__global__ __launch_bounds__(256)
void transpose_generic(const float* __restrict__ src, unsigned short* __restrict__ dst,
                       int ldsrc, int lddst) {
  __shared__ float t[32][33];
  int k0 = blockIdx.x * 32, n0 = blockIdx.y * 32;
  int tx = threadIdx.x, ty = threadIdx.y;
  for (int r = ty; r < 32; r += 8)
    t[r][tx] = src[(size_t)(k0 + r) * ldsrc + n0 + tx];
  __syncthreads();
  for (int r = ty; r < 32; r += 8)
    dst[(size_t)(n0 + r) * lddst + k0 + tx] = f2b(t[tx][r]);
}

// Wq/Wk/Wv: [H, D, DK] fp32  ->  Wqkvt: bf16 [3072][1024], col n = which*1024 + h*64 + dk
// Q block pre-scaled by 1/sqrt(DK) = 0.125
__global__ __launch_bounds__(256)
void transpose_qkv(const float* __restrict__ Wq, const float* __restrict__ Wk,
                   const float* __restrict__ Wv, unsigned short* __restrict__ dst) {
  int z = blockIdx.z, which = z / 16, h = z % 16;
  const float* src = (which == 0 ? Wq : which == 1 ? Wk : Wv) + (size_t)h * ND * NDK;
  float scale = (which == 0) ? 0.125f : 1.0f;
  unsigned short* d = dst + (size_t)(which * 1024 + h * 64) * ND;
  __shared__ float t[32][33];
  int k0 = blockIdx.x * 32, n0 = blockIdx.y * 32;
  int tx = threadIdx.x, ty = threadIdx.y;
  for (int r = ty; r < 32; r += 8)
    t[r][tx] = src[(size_t)(k0 + r) * NDK + n0 + tx];
  __syncthreads();
  for (int r = ty; r < 32; r += 8)
    d[(size_t)(n0 + r) * ND + k0 + tx] = f2b(t[tx][r] * scale);
}

__global__ __launch_bounds__(256)
void pack_bias(const float* __restrict__ bq, const float* __restrict__ bk,
               const float* __restrict__ bv, float* __restrict__ out) {
  int i = blockIdx.x * 256 + threadIdx.x;
  if (i >= 3072) return;
  float v = (i < 1024) ? bq[i] * 0.125f : (i < 2048 ? bk[i - 1024] : bv[i - 2048]);
  out[i] = v;
}

// ---------------- GEMM: C = A(bf16 [M][K]) @ Bt(bf16 [N][K])^T + bias ----------------
// m97 structure: 128x128 tile, BK=32, 4 waves (2x2), global_load_lds width 16.
// EPI: 0 = bf16 store, 1 = f32 store, 2 = bf16 tanh store

template<int EPI>
__global__ __launch_bounds__(256)
void gemm_bt(const unsigned short* __restrict__ A, const unsigned short* __restrict__ Bt,
             const float* __restrict__ bias, void* __restrict__ Cout,
             int M, int N, int K)
{
  __shared__ __align__(16) unsigned short As[128 * 32];
  __shared__ __align__(16) unsigned short Bs[128 * 32];
  const int n0 = blockIdx.x * 128;
  const int m0 = blockIdx.y * 128;
  const int tid = threadIdx.x;
  const int wave = tid >> 6, lane = tid & 63;
  const int l16 = lane & 15, lhi = lane >> 4;
  const int wr = wave >> 1, wc = wave & 1;
  const int ca = wave * 2;          // this wave stages chunks ca, ca+1 (1 KiB each)
  const int srow = lane >> 2;       // row within 16-row chunk
  const int skp = (lane & 3) * 8;   // bf16 k-offset of this lane's 16B

  f32x4 acc[4][4] = {};

  for (int k0 = 0; k0 < K; k0 += 32) {
    __syncthreads();
#pragma unroll
    for (int c = ca; c < ca + 2; ++c)
      gload_lds16(A + (size_t)(m0 + c * 16 + srow) * K + (k0 + skp), &As[c * 512]);
#pragma unroll
    for (int c = ca; c < ca + 2; ++c)
      gload_lds16(Bt + (size_t)(n0 + c * 16 + srow) * K + (k0 + skp), &Bs[c * 512]);
    __syncthreads();

    short8 af[4], bf[4];
#pragma unroll
    for (int i = 0; i < 4; ++i)
      af[i] = *(const short8*)&As[(wr * 64 + i * 16 + l16) * 32 + lhi * 8];
#pragma unroll
    for (int j = 0; j < 4; ++j)
      bf[j] = *(const short8*)&Bs[(wc * 64 + j * 16 + l16) * 32 + lhi * 8];
#pragma unroll
    for (int i = 0; i < 4; ++i)
#pragma unroll
      for (int j = 0; j < 4; ++j)
        acc[i][j] = __builtin_amdgcn_mfma_f32_16x16x32_bf16(af[i], bf[j], acc[i][j], 0, 0, 0);
  }

#pragma unroll
  for (int i = 0; i < 4; ++i) {
    const int row = m0 + wr * 64 + i * 16 + lhi * 4;
#pragma unroll
    for (int j = 0; j < 4; ++j) {
      const int col = n0 + wc * 64 + j * 16 + l16;
      const float bv = bias[col];
#pragma unroll
      for (int r = 0; r < 4; ++r) {
        float v = acc[i][j][r] + bv;
        size_t idx = (size_t)(row + r) * N + col;
        if (EPI == 0)      ((unsigned short*)Cout)[idx] = f2b(v);
        else if (EPI == 1) ((float*)Cout)[idx] = v;
        else               ((unsigned short*)Cout)[idx] = f2b(tanhf(v));
      }
    }
  }
}

// ---------------- flash attention ----------------
// qkv: bf16 [8192][3072] (q | k | v blocks of 1024 cols, head h at h*64; q pre-scaled)
// ctx: bf16 [8192][1024]  (heads concatenated)
// grid: (S/64, B*H); 4 waves, each owns 16 q-rows.

__global__ __launch_bounds__(256)
void attn_fwd(const unsigned short* __restrict__ qkv, unsigned short* __restrict__ ctx)
{
  const int qt = blockIdx.x;
  const int bh = blockIdx.y;
  const int b = bh >> 4, h = bh & 15;
  const int row0 = b * NS + qt * 64;
  const int qc = h * 64, kc = ND + h * 64, vc = 2 * ND + h * 64;
  const int tid = threadIdx.x;
  const int wave = tid >> 6, lane = tid & 63;
  const int l16 = lane & 15, lhi = lane >> 4;

  __shared__ __align__(16) unsigned short Ks[64 * 64];   // [key][feat]
  __shared__ __align__(16) unsigned short Vts[64 * 64];  // [dk][key] (transposed)
  __shared__ __align__(16) unsigned short Ps[64 * 64];   // [qrow][key]

  short8 qf[2];
  {
    const unsigned short* qrow = qkv + (size_t)(row0 + wave * 16 + l16) * 3072 + qc;
    qf[0] = *(const short8*)(qrow + lhi * 8);
    qf[1] = *(const short8*)(qrow + 32 + lhi * 8);
  }

  f32x4 o[4] = {};
  float mr[4] = {-INFINITY, -INFINITY, -INFINITY, -INFINITY};
  float lr[4] = {0.f, 0.f, 0.f, 0.f};

  for (int kt = 0; kt < NS / 64; ++kt) {
    __syncthreads();
    const int krow0 = b * NS + kt * 64;
#pragma unroll
    for (int it = 0; it < 2; ++it) {
      const int c = tid + it * 256;          // 0..511 chunk id
      const int key = c >> 3, kp = (c & 7) * 8;
      const size_t gb = (size_t)(krow0 + key) * 3072;
      *(short8*)&Ks[key * 64 + kp] = *(const short8*)&qkv[gb + kc + kp];
      short8 vv = *(const short8*)&qkv[gb + vc + kp];
#pragma unroll
      for (int e = 0; e < 8; ++e)
        Vts[(kp + e) * 64 + key] = (unsigned short)vv[e];
    }
    __syncthreads();

    // scores: S = Q @ K^T, per wave 16x64
    f32x4 s[4] = {};
#pragma unroll
    for (int c = 0; c < 2; ++c)
#pragma unroll
      for (int j = 0; j < 4; ++j) {
        short8 kf = *(const short8*)&Ks[(j * 16 + l16) * 64 + c * 32 + lhi * 8];
        s[j] = __builtin_amdgcn_mfma_f32_16x16x32_bf16(qf[c], kf, s[j], 0, 0, 0);
      }

    // online softmax (fp32). C/D layout: row=lhi*4+r, col=j*16+l16
#pragma unroll
    for (int r = 0; r < 4; ++r) {
      float mx = fmaxf(fmaxf(s[0][r], s[1][r]), fmaxf(s[2][r], s[3][r]));
#pragma unroll
      for (int d = 1; d < 16; d <<= 1) mx = fmaxf(mx, __shfl_xor(mx, d));
      const float nm = fmaxf(mr[r], mx);
      const float al = __expf(mr[r] - nm);
      mr[r] = nm;
      float rs = 0.f;
#pragma unroll
      for (int j = 0; j < 4; ++j) { float e = __expf(s[j][r] - nm); s[j][r] = e; rs += e; }
#pragma unroll
      for (int d = 1; d < 16; d <<= 1) rs += __shfl_xor(rs, d);
      lr[r] = lr[r] * al + rs;
#pragma unroll
      for (int j = 0; j < 4; ++j) o[j][r] *= al;
    }

    // P -> LDS (bf16), each wave its own 16 rows
#pragma unroll
    for (int j = 0; j < 4; ++j)
#pragma unroll
      for (int r = 0; r < 4; ++r)
        Ps[(wave * 16 + lhi * 4 + r) * 64 + j * 16 + l16] = f2b(s[j][r]);
    __syncthreads();

    // O += P @ V
#pragma unroll
    for (int c = 0; c < 2; ++c) {
      short8 pf = *(const short8*)&Ps[(wave * 16 + l16) * 64 + c * 32 + lhi * 8];
#pragma unroll
      for (int j = 0; j < 4; ++j) {
        short8 vf = *(const short8*)&Vts[(j * 16 + l16) * 64 + c * 32 + lhi * 8];
        o[j] = __builtin_amdgcn_mfma_f32_16x16x32_bf16(pf, vf, o[j], 0, 0, 0);
      }
    }
  }

#pragma unroll
  for (int j = 0; j < 4; ++j)
#pragma unroll
    for (int r = 0; r < 4; ++r) {
      const int row = row0 + wave * 16 + lhi * 4 + r;
      ctx[(size_t)row * ND + h * 64 + j * 16 + l16] = f2b(o[j][r] / lr[r]);
    }
}

// ---------------- fused residual + LayerNorm ----------------
// out = LN(xa + xb); WB: also write bf16 copy. (no __restrict__: LN2 aliases xb/of)

template<int WB>
__global__ __launch_bounds__(256)
void ln_fused(const float* xa, const float* xb,
              const float* g, const float* beta,
              float* of, unsigned short* ob)
{
  const int row = blockIdx.x;
  const int tid = threadIdx.x;
  const int wave = tid >> 6, lane = tid & 63;
  __shared__ float r1[4], r2[4];
  float4 a = ((const float4*)(xa + (size_t)row * ND))[tid];
  float4 b = ((const float4*)(xb + (size_t)row * ND))[tid];
  float v0 = a.x + b.x, v1 = a.y + b.y, v2 = a.z + b.z, v3 = a.w + b.w;
  float sm = v0 + v1 + v2 + v3;
#pragma unroll
  for (int d = 1; d < 64; d <<= 1) sm += __shfl_xor(sm, d);
  if (lane == 0) r1[wave] = sm;
  __syncthreads();
  const float mu = (r1[0] + r1[1] + r1[2] + r1[3]) * (1.0f / ND);
  const float d0 = v0 - mu, d1 = v1 - mu, d2 = v2 - mu, d3 = v3 - mu;
  float vs = d0 * d0 + d1 * d1 + d2 * d2 + d3 * d3;
#pragma unroll
  for (int d = 1; d < 64; d <<= 1) vs += __shfl_xor(vs, d);
  if (lane == 0) r2[wave] = vs;
  __syncthreads();
  const float var = (r2[0] + r2[1] + r2[2] + r2[3]) * (1.0f / ND);
  const float inv = rsqrtf(var + 1e-5f);
  float4 gg = ((const float4*)g)[tid];
  float4 bb = ((const float4*)beta)[tid];
  float o0 = d0 * inv * gg.x + bb.x;
  float o1 = d1 * inv * gg.y + bb.y;
  float o2 = d2 * inv * gg.z + bb.z;
  float o3 = d3 * inv * gg.w + bb.w;
  float4 ov; ov.x = o0; ov.y = o1; ov.z = o2; ov.w = o3;
  ((float4*)(of + (size_t)row * ND))[tid] = ov;
  if (WB) {
    ushort4 w; w.x = f2b(o0); w.y = f2b(o1); w.z = f2b(o2); w.w = f2b(o3);
    ((ushort4*)(ob + (size_t)row * ND))[tid] = w;
  }
}

// ---------------- launch ----------------

extern "C" void kernel_launch(void* const* d_in, const int* in_sizes, int n_in,
                              void* d_out, int out_size, void* d_ws, size_t ws_size,
                              hipStream_t stream)
{
  (void)in_sizes; (void)n_in; (void)out_size; (void)ws_size;
  const float* x   = (const float*)d_in[0];
  const float* Wq  = (const float*)d_in[1];
  const float* bq  = (const float*)d_in[2];
  const float* Wk  = (const float*)d_in[3];
  const float* bk  = (const float*)d_in[4];
  const float* Wv  = (const float*)d_in[5];
  const float* bv  = (const float*)d_in[6];
  const float* Wo  = (const float*)d_in[7];
  const float* bo  = (const float*)d_in[8];
  const float* g1  = (const float*)d_in[9];
  const float* be1 = (const float*)d_in[10];
  const float* W1  = (const float*)d_in[11];
  const float* b1  = (const float*)d_in[12];
  const float* W2  = (const float*)d_in[13];
  const float* b2  = (const float*)d_in[14];
  const float* g2  = (const float*)d_in[15];
  const float* be2 = (const float*)d_in[16];

  char* ws = (char*)d_ws;
  const size_t MB = 1ull << 20;
  // layout (137 MiB total, with overlays):
  unsigned short* x_bf  = (unsigned short*)(ws);             // 16 MiB, dead after G1
  unsigned short* qkv   = (unsigned short*)(ws + 16 * MB);   // 48 MiB, dead after attn
  unsigned short* ff1   = (unsigned short*)(ws);             // 64 MiB, overlays x_bf+qkv
  unsigned short* ctx   = (unsigned short*)(ws + 64 * MB);   // 16 MiB, dead after G2
  unsigned short* h_bf  = (unsigned short*)(ws + 64 * MB);   // 16 MiB, overlays ctx
  unsigned short* Wqkvt = (unsigned short*)(ws + 80 * MB);   // 6 MiB
  unsigned short* Wot   = (unsigned short*)(ws + 86 * MB);   // 2 MiB
  unsigned short* W1t   = (unsigned short*)(ws + 88 * MB);   // 8 MiB
  unsigned short* W2t   = (unsigned short*)(ws + 96 * MB);   // 8 MiB
  float*          bqkv  = (float*)(ws + 104 * MB);           // 12 KiB
  float*          h_f   = (float*)(ws + 105 * MB);           // 32 MiB
  float*          gout  = (float*)d_out;                     // 32 MiB fp32 scratch (attn_out / ff_out)

  // prep
  cvt_f32_bf16<<<NM * ND / 4 / 256, 256, 0, stream>>>(x, x_bf, NM * ND / 4);
  transpose_qkv<<<dim3(32, 2, 48), dim3(32, 8), 0, stream>>>(Wq, Wk, Wv, Wqkvt);
  transpose_generic<<<dim3(32, 32), dim3(32, 8), 0, stream>>>(Wo, Wot, 1024, 1024);
  transpose_generic<<<dim3(32, 128), dim3(32, 8), 0, stream>>>(W1, W1t, 4096, 1024);
  transpose_generic<<<dim3(128, 32), dim3(32, 8), 0, stream>>>(W2, W2t, 1024, 4096);
  pack_bias<<<12, 256, 0, stream>>>(bq, bk, bv, bqkv);

  // QKV projection (q pre-scaled by 1/8)
  gemm_bt<0><<<dim3(3072 / 128, NM / 128), 256, 0, stream>>>(x_bf, Wqkvt, bqkv, qkv, NM, 3072, 1024);
  // attention
  attn_fwd<<<dim3(NS / 64, NB * NH), 256, 0, stream>>>(qkv, ctx);
  // output projection -> fp32 (into d_out scratch)
  gemm_bt<1><<<dim3(1024 / 128, NM / 128), 256, 0, stream>>>(ctx, Wot, bo, gout, NM, 1024, 1024);
  // h = LN(x + attn_out)
  ln_fused<1><<<NM, 256, 0, stream>>>(x, gout, g1, be1, h_f, h_bf);
  // FFN1 with tanh
  gemm_bt<2><<<dim3(4096 / 128, NM / 128), 256, 0, stream>>>(h_bf, W1t, b1, ff1, NM, 4096, 1024);
  // FFN2 -> fp32 (d_out scratch)
  gemm_bt<1><<<dim3(1024 / 128, NM / 128), 256, 0, stream>>>(ff1, W2t, b2, gout, NM, 1024, 4096);
  // out = LN(h + ff)  (reads d_out, writes d_out: per-thread read-before-write, safe)
  ln_fused<0><<<NM, 256, 0, stream>>>(h_f, gout, g2, be2, (float*)d_out, nullptr);
}

// Round 2
// 623.719 us; speedup vs baseline: 1.2601x; 1.2601x over previous
//
#include <hip/hip_runtime.h>
#include <hip/hip_bf16.h>
#include <math.h>

typedef __attribute__((ext_vector_type(8))) short short8;
typedef __attribute__((ext_vector_type(4))) float f32x4;

#define NB 4
#define NS 2048
#define ND 1024
#define NH 16
#define NDK 64
#define NF 4096
#define NM (NB*NS)   // 8192 rows total

// 1/sqrt(DK) * log2(e): scores come out of QK^T already in log2 domain
#define QSCALE 0.18033688f

__device__ __forceinline__ unsigned short f2b(float f) {
  union { __hip_bfloat16 h; unsigned short u; } c;
  c.h = __float2bfloat16(f);
  return c.u;
}

__device__ __forceinline__ void gload_lds16(const void* g, void* l) {
  __builtin_amdgcn_global_load_lds((const __attribute__((address_space(1))) void*)g,
                                   (__attribute__((address_space(3))) void*)l,
                                   16, 0, 0);
}

// ---------------- conversions / weight prep ----------------

__global__ __launch_bounds__(256)
void cvt_f32_bf16(const float* __restrict__ in, unsigned short* __restrict__ out, int n4) {
  int i = blockIdx.x * 256 + threadIdx.x;
  if (i >= n4) return;
  float4 v = ((const float4*)in)[i];
  ushort4 o;
  o.x = f2b(v.x); o.y = f2b(v.y); o.z = f2b(v.z); o.w = f2b(v.w);
  ((ushort4*)out)[i] = o;
}

// src: fp32 [K][N] (row stride ldsrc); dst: bf16 [N][K] (row stride lddst)
__global__ __launch_bounds__(256)
void transpose_generic(const float* __restrict__ src, unsigned short* __restrict__ dst,
                       int ldsrc, int lddst) {
  __shared__ float t[32][33];
  int k0 = blockIdx.x * 32, n0 = blockIdx.y * 32;
  int tx = threadIdx.x, ty = threadIdx.y;
  for (int r = ty; r < 32; r += 8)
    t[r][tx] = src[(size_t)(k0 + r) * ldsrc + n0 + tx];
  __syncthreads();
  for (int r = ty; r < 32; r += 8)
    dst[(size_t)(n0 + r) * lddst + k0 + tx] = f2b(t[tx][r]);
}

// Wq/Wk/Wv: [H, D, DK] fp32  ->  Wqkvt: bf16 [3072][1024]
// Q block pre-scaled by 1/sqrt(DK)*log2e
__global__ __launch_bounds__(256)
void transpose_qkv(const float* __restrict__ Wq, const float* __restrict__ Wk,
                   const float* __restrict__ Wv, unsigned short* __restrict__ dst) {
  int z = blockIdx.z, which = z / 16, h = z % 16;
  const float* src = (which == 0 ? Wq : which == 1 ? Wk : Wv) + (size_t)h * ND * NDK;
  float scale = (which == 0) ? QSCALE : 1.0f;
  unsigned short* d = dst + (size_t)(which * 1024 + h * 64) * ND;
  __shared__ float t[32][33];
  int k0 = blockIdx.x * 32, n0 = blockIdx.y * 32;
  int tx = threadIdx.x, ty = threadIdx.y;
  for (int r = ty; r < 32; r += 8)
    t[r][tx] = src[(size_t)(k0 + r) * NDK + n0 + tx];
  __syncthreads();
  for (int r = ty; r < 32; r += 8)
    d[(size_t)(n0 + r) * ND + k0 + tx] = f2b(t[tx][r] * scale);
}

__global__ __launch_bounds__(256)
void pack_bias(const float* __restrict__ bq, const float* __restrict__ bk,
               const float* __restrict__ bv, float* __restrict__ out) {
  int i = blockIdx.x * 256 + threadIdx.x;
  if (i >= 3072) return;
  float v = (i < 1024) ? bq[i] * QSCALE : (i < 2048 ? bk[i - 1024] : bv[i - 2048]);
  out[i] = v;
}

// V transpose: qkv [8192][3072] (v at col 2048+h*64) -> vt [64 bh][64 d][2048 s]
__global__ __launch_bounds__(256)
void transpose_v(const unsigned short* __restrict__ qkv, unsigned short* __restrict__ vt) {
  __shared__ unsigned short t[32][33];
  int bh = blockIdx.z; int b = bh >> 4, h = bh & 15;
  int s0 = blockIdx.x * 32;
  int d0 = blockIdx.y * 32;
  int tx = threadIdx.x, ty = threadIdx.y;
  for (int r = ty; r < 32; r += 8)
    t[r][tx] = qkv[(size_t)(b * NS + s0 + r) * 3072 + 2048 + h * 64 + d0 + tx];
  __syncthreads();
  for (int r = ty; r < 32; r += 8)
    vt[((size_t)bh * 64 + d0 + r) * NS + s0 + tx] = t[tx][r];
}

// ---------------- GEMM: C = A(bf16 [M][K]) @ Bt(bf16 [N][K])^T + bias ----------------

template<int EPI>
__global__ __launch_bounds__(256)
void gemm_bt(const unsigned short* __restrict__ A, const unsigned short* __restrict__ Bt,
             const float* __restrict__ bias, void* __restrict__ Cout,
             int M, int N, int K)
{
  __shared__ __align__(16) unsigned short As[128 * 32];
  __shared__ __align__(16) unsigned short Bs[128 * 32];
  const int n0 = blockIdx.x * 128;
  const int m0 = blockIdx.y * 128;
  const int tid = threadIdx.x;
  const int wave = tid >> 6, lane = tid & 63;
  const int l16 = lane & 15, lhi = lane >> 4;
  const int wr = wave >> 1, wc = wave & 1;
  const int ca = wave * 2;
  const int srow = lane >> 2;
  const int skp = (lane & 3) * 8;

  f32x4 acc[4][4] = {};

  for (int k0 = 0; k0 < K; k0 += 32) {
    __syncthreads();
#pragma unroll
    for (int c = ca; c < ca + 2; ++c)
      gload_lds16(A + (size_t)(m0 + c * 16 + srow) * K + (k0 + skp), &As[c * 512]);
#pragma unroll
    for (int c = ca; c < ca + 2; ++c)
      gload_lds16(Bt + (size_t)(n0 + c * 16 + srow) * K + (k0 + skp), &Bs[c * 512]);
    __syncthreads();

    short8 af[4], bf[4];
#pragma unroll
    for (int i = 0; i < 4; ++i)
      af[i] = *(const short8*)&As[(wr * 64 + i * 16 + l16) * 32 + lhi * 8];
#pragma unroll
    for (int j = 0; j < 4; ++j)
      bf[j] = *(const short8*)&Bs[(wc * 64 + j * 16 + l16) * 32 + lhi * 8];
#pragma unroll
    for (int i = 0; i < 4; ++i)
#pragma unroll
      for (int j = 0; j < 4; ++j)
        acc[i][j] = __builtin_amdgcn_mfma_f32_16x16x32_bf16(af[i], bf[j], acc[i][j], 0, 0, 0);
  }

#pragma unroll
  for (int i = 0; i < 4; ++i) {
    const int row = m0 + wr * 64 + i * 16 + lhi * 4;
#pragma unroll
    for (int j = 0; j < 4; ++j) {
      const int col = n0 + wc * 64 + j * 16 + l16;
      const float bv = bias[col];
#pragma unroll
      for (int r = 0; r < 4; ++r) {
        float v = acc[i][j][r] + bv;
        size_t idx = (size_t)(row + r) * N + col;
        if (EPI == 0)      ((unsigned short*)Cout)[idx] = f2b(v);
        else if (EPI == 1) ((float*)Cout)[idx] = v;
        else               ((unsigned short*)Cout)[idx] = f2b(tanhf(v));
      }
    }
  }
}

// ---------------- flash attention (swizzled LDS, double-buffered) ----------------
// qkv: bf16 [8192][3072] (q pre-scaled to log2 domain); vtg: bf16 [64][64][2048]
// ctx: bf16 [8192][1024]. 1D grid of 2048 blocks (XCD-swizzled), 4 waves x 16 q-rows.

__global__ __launch_bounds__(256)
void attn_fwd(const unsigned short* __restrict__ qkv, const unsigned short* __restrict__ vtg,
              unsigned short* __restrict__ ctx)
{
  // bijective XCD swizzle: 2048 blocks = 8 XCDs x 256
  const int id = blockIdx.x;
  const int swz = (id & 7) * 256 + (id >> 3);
  const int qt = swz & 31;
  const int bh = swz >> 5;
  const int b = bh >> 4, h = bh & 15;
  const int row0 = b * NS + qt * 64;
  const int tid = threadIdx.x;
  const int wave = tid >> 6, lane = tid & 63;
  const int l16 = lane & 15, lhi = lane >> 4;

  __shared__ __align__(16) unsigned short Ks[2][64 * 64];
  __shared__ __align__(16) unsigned short Vs[2][64 * 64];   // [d][key], swizzled
  __shared__ __align__(16) unsigned short Ps[4][16 * 64];   // wave-private, swizzled

  const unsigned short* kbase = qkv + ND + (size_t)h * 64;      // + row*3072
  const unsigned short* vbase = vtg + (size_t)bh * 64 * NS;     // + d*NS + key

  // staging: chunk c in [0,512): row=c>>3, swizzled slot sb=(c&7)*16 bytes
  // inverse swizzle on global source: featByte = sb ^ ((row&7)<<4)
  const int c0 = tid, c1 = 256 + tid;
  const int r0 = c0 >> 3, r1 = c1 >> 3;
  const int f0 = ((((c0 & 7) << 4) ^ ((r0 & 7) << 4)) >> 1);   // element offset in row
  const int f1 = ((((c1 & 7) << 4) ^ ((r1 & 7) << 4)) >> 1);
  const int ldsb0 = wave * 512;          // element base for inst 0 (chunk = wave*64 + lane)
  const int ldsb1 = 2048 + wave * 512;   // element base for inst 1

  // Q fragments (A operand, rows = this wave's 16 q-rows)
  short8 qf[2];
  {
    const unsigned short* qrow = qkv + (size_t)(row0 + wave * 16 + l16) * 3072 + h * 64;
    qf[0] = *(const short8*)(qrow + lhi * 8);
    qf[1] = *(const short8*)(qrow + 32 + lhi * 8);
  }

  f32x4 o[4] = {};
  float mr[4] = {-INFINITY, -INFINITY, -INFINITY, -INFINITY};
  float lr[4] = {0.f, 0.f, 0.f, 0.f};

  auto STAGE = [&](int buf, int kt) {
    const size_t kr = (size_t)(b * NS + kt * 64);
    const int kb64 = kt * 64;
    gload_lds16(kbase + (kr + r0) * 3072 + f0, &Ks[buf][ldsb0]);
    gload_lds16(kbase + (kr + r1) * 3072 + f1, &Ks[buf][ldsb1]);
    gload_lds16(vbase + (size_t)r0 * NS + kb64 + f0, &Vs[buf][ldsb0]);
    gload_lds16(vbase + (size_t)r1 * NS + kb64 + f1, &Vs[buf][ldsb1]);
  };

  auto COMPUTE = [&](int buf) {
    const char* kb = (const char*)&Ks[buf][0];
    const char* vb = (const char*)&Vs[buf][0];
    char* pb = (char*)&Ps[wave][0];

    // S = Q @ K^T (log2 domain)
    f32x4 s[4] = {};
#pragma unroll
    for (int c = 0; c < 2; ++c)
#pragma unroll
      for (int j = 0; j < 4; ++j) {
        const int row = j * 16 + l16;
        short8 kf = *(const short8*)(kb + row * 128 + ((c * 64 + lhi * 16) ^ ((row & 7) << 4)));
        s[j] = __builtin_amdgcn_mfma_f32_16x16x32_bf16(qf[c], kf, s[j], 0, 0, 0);
      }

    // online softmax, exp2 domain, defer-max (T13)
    float pmax[4];
#pragma unroll
    for (int r = 0; r < 4; ++r) {
      float mx = fmaxf(fmaxf(s[0][r], s[1][r]), fmaxf(s[2][r], s[3][r]));
#pragma unroll
      for (int d = 1; d < 16; d <<= 1) mx = fmaxf(mx, __shfl_xor(mx, d));
      pmax[r] = mx;
    }
    bool need = (pmax[0] > mr[0] + 8.f) | (pmax[1] > mr[1] + 8.f) |
                (pmax[2] > mr[2] + 8.f) | (pmax[3] > mr[3] + 8.f);
    if (__any(need)) {
#pragma unroll
      for (int r = 0; r < 4; ++r) {
        const float nm = fmaxf(mr[r], pmax[r]);
        const float al = __builtin_amdgcn_exp2f(mr[r] - nm);
        mr[r] = nm;
        lr[r] *= al;
#pragma unroll
        for (int j = 0; j < 4; ++j) o[j][r] *= al;
      }
    }
#pragma unroll
    for (int r = 0; r < 4; ++r) {
      float rs = 0.f;
#pragma unroll
      for (int j = 0; j < 4; ++j) {
        float e = __builtin_amdgcn_exp2f(s[j][r] - mr[r]);
        s[j][r] = e; rs += e;
      }
#pragma unroll
      for (int d = 1; d < 16; d <<= 1) rs += __shfl_xor(rs, d);
      lr[r] += rs;
    }

    // P -> LDS (bf16, swizzled, wave-private)
#pragma unroll
    for (int j = 0; j < 4; ++j)
#pragma unroll
      for (int r = 0; r < 4; ++r) {
        const int qr = lhi * 4 + r;
        *(unsigned short*)(pb + qr * 128 + ((2 * (j * 16 + l16)) ^ ((qr & 7) << 4))) = f2b(s[j][r]);
      }

    // O += P @ V
#pragma unroll
    for (int c = 0; c < 2; ++c) {
      short8 pf = *(const short8*)(pb + l16 * 128 + ((c * 64 + lhi * 16) ^ ((l16 & 7) << 4)));
#pragma unroll
      for (int j = 0; j < 4; ++j) {
        const int row = j * 16 + l16;
        short8 vf = *(const short8*)(vb + row * 128 + ((c * 64 + lhi * 16) ^ ((row & 7) << 4)));
        o[j] = __builtin_amdgcn_mfma_f32_16x16x32_bf16(pf, vf, o[j], 0, 0, 0);
      }
    }
  };

  STAGE(0, 0);
  __syncthreads();
  int cur = 0;
  for (int kt = 0; kt < NS / 64 - 1; ++kt) {
    STAGE(cur ^ 1, kt + 1);
    COMPUTE(cur);
    __syncthreads();
    cur ^= 1;
  }
  COMPUTE(cur);

  float rinv[4];
#pragma unroll
  for (int r = 0; r < 4; ++r) rinv[r] = 1.0f / lr[r];
#pragma unroll
  for (int j = 0; j < 4; ++j)
#pragma unroll
    for (int r = 0; r < 4; ++r) {
      const int row = row0 + wave * 16 + lhi * 4 + r;
      ctx[(size_t)row * ND + h * 64 + j * 16 + l16] = f2b(o[j][r] * rinv[r]);
    }
}

// ---------------- fused residual + LayerNorm ----------------

template<int WB>
__global__ __launch_bounds__(256)
void ln_fused(const float* xa, const float* xb,
              const float* g, const float* beta,
              float* of, unsigned short* ob)
{
  const int row = blockIdx.x;
  const int tid = threadIdx.x;
  const int wave = tid >> 6, lane = tid & 63;
  __shared__ float r1[4], r2[4];
  float4 a = ((const float4*)(xa + (size_t)row * ND))[tid];
  float4 b = ((const float4*)(xb + (size_t)row * ND))[tid];
  float v0 = a.x + b.x, v1 = a.y + b.y, v2 = a.z + b.z, v3 = a.w + b.w;
  float sm = v0 + v1 + v2 + v3;
#pragma unroll
  for (int d = 1; d < 64; d <<= 1) sm += __shfl_xor(sm, d);
  if (lane == 0) r1[wave] = sm;
  __syncthreads();
  const float mu = (r1[0] + r1[1] + r1[2] + r1[3]) * (1.0f / ND);
  const float d0 = v0 - mu, d1 = v1 - mu, d2 = v2 - mu, d3 = v3 - mu;
  float vs = d0 * d0 + d1 * d1 + d2 * d2 + d3 * d3;
#pragma unroll
  for (int d = 1; d < 64; d <<= 1) vs += __shfl_xor(vs, d);
  if (lane == 0) r2[wave] = vs;
  __syncthreads();
  const float var = (r2[0] + r2[1] + r2[2] + r2[3]) * (1.0f / ND);
  const float inv = rsqrtf(var + 1e-5f);
  float4 gg = ((const float4*)g)[tid];
  float4 bb = ((const float4*)beta)[tid];
  float o0 = d0 * inv * gg.x + bb.x;
  float o1 = d1 * inv * gg.y + bb.y;
  float o2 = d2 * inv * gg.z + bb.z;
  float o3 = d3 * inv * gg.w + bb.w;
  float4 ov; ov.x = o0; ov.y = o1; ov.z = o2; ov.w = o3;
  ((float4*)(of + (size_t)row * ND))[tid] = ov;
  if (WB) {
    ushort4 w; w.x = f2b(o0); w.y = f2b(o1); w.z = f2b(o2); w.w = f2b(o3);
    ((ushort4*)(ob + (size_t)row * ND))[tid] = w;
  }
}

// ---------------- launch ----------------

extern "C" void kernel_launch(void* const* d_in, const int* in_sizes, int n_in,
                              void* d_out, int out_size, void* d_ws, size_t ws_size,
                              hipStream_t stream)
{
  (void)in_sizes; (void)n_in; (void)out_size; (void)ws_size;
  const float* x   = (const float*)d_in[0];
  const float* Wq  = (const float*)d_in[1];
  const float* bq  = (const float*)d_in[2];
  const float* Wk  = (const float*)d_in[3];
  const float* bk  = (const float*)d_in[4];
  const float* Wv  = (const float*)d_in[5];
  const float* bv  = (const float*)d_in[6];
  const float* Wo  = (const float*)d_in[7];
  const float* bo  = (const float*)d_in[8];
  const float* g1  = (const float*)d_in[9];
  const float* be1 = (const float*)d_in[10];
  const float* W1  = (const float*)d_in[11];
  const float* b1  = (const float*)d_in[12];
  const float* W2  = (const float*)d_in[13];
  const float* b2  = (const float*)d_in[14];
  const float* g2  = (const float*)d_in[15];
  const float* be2 = (const float*)d_in[16];

  char* ws = (char*)d_ws;
  const size_t MB = 1ull << 20;
  unsigned short* x_bf  = (unsigned short*)(ws);             // 16 MiB, dead after G1
  unsigned short* vtg   = (unsigned short*)(ws);             // 16 MiB, overlays x_bf (after G1)
  unsigned short* qkv   = (unsigned short*)(ws + 16 * MB);   // 48 MiB, dead after attn
  unsigned short* ff1   = (unsigned short*)(ws);             // 64 MiB, overlays vtg+qkv
  unsigned short* ctx   = (unsigned short*)(ws + 64 * MB);   // 16 MiB, dead after G2
  unsigned short* h_bf  = (unsigned short*)(ws + 64 * MB);   // 16 MiB, overlays ctx
  unsigned short* Wqkvt = (unsigned short*)(ws + 80 * MB);   // 6 MiB
  unsigned short* Wot   = (unsigned short*)(ws + 86 * MB);   // 2 MiB
  unsigned short* W1t   = (unsigned short*)(ws + 88 * MB);   // 8 MiB
  unsigned short* W2t   = (unsigned short*)(ws + 96 * MB);   // 8 MiB
  float*          bqkv  = (float*)(ws + 104 * MB);           // 12 KiB
  float*          h_f   = (float*)(ws + 105 * MB);           // 32 MiB
  float*          gout  = (float*)d_out;                     // 32 MiB fp32 scratch

  cvt_f32_bf16<<<NM * ND / 4 / 256, 256, 0, stream>>>(x, x_bf, NM * ND / 4);
  transpose_qkv<<<dim3(32, 2, 48), dim3(32, 8), 0, stream>>>(Wq, Wk, Wv, Wqkvt);
  transpose_generic<<<dim3(32, 32), dim3(32, 8), 0, stream>>>(Wo, Wot, 1024, 1024);
  transpose_generic<<<dim3(32, 128), dim3(32, 8), 0, stream>>>(W1, W1t, 4096, 1024);
  transpose_generic<<<dim3(128, 32), dim3(32, 8), 0, stream>>>(W2, W2t, 1024, 4096);
  pack_bias<<<12, 256, 0, stream>>>(bq, bk, bv, bqkv);

  // QKV projection (q pre-scaled into log2 domain)
  gemm_bt<0><<<dim3(3072 / 128, NM / 128), 256, 0, stream>>>(x_bf, Wqkvt, bqkv, qkv, NM, 3072, 1024);
  // V transpose (x_bf now dead; vtg overlays it)
  transpose_v<<<dim3(64, 2, 64), dim3(32, 8), 0, stream>>>(qkv, vtg);
  // attention
  attn_fwd<<<2048, 256, 0, stream>>>(qkv, vtg, ctx);
  // output projection -> fp32 (into d_out scratch)
  gemm_bt<1><<<dim3(1024 / 128, NM / 128), 256, 0, stream>>>(ctx, Wot, bo, gout, NM, 1024, 1024);
  // h = LN(x + attn_out)
  ln_fused<1><<<NM, 256, 0, stream>>>(x, gout, g1, be1, h_f, h_bf);
  // FFN1 with tanh
  gemm_bt<2><<<dim3(4096 / 128, NM / 128), 256, 0, stream>>>(h_bf, W1t, b1, ff1, NM, 4096, 1024);
  // FFN2 -> fp32 (d_out scratch)
  gemm_bt<1><<<dim3(1024 / 128, NM / 128), 256, 0, stream>>>(ff1, W2t, b2, gout, NM, 1024, 4096);
  // out = LN(h + ff)
  ln_fused<0><<<NM, 256, 0, stream>>>(h_f, gout, g2, be2, (float*)d_out, nullptr);
}

// Round 3
// 550.483 us; speedup vs baseline: 1.4277x; 1.1330x over previous
//
#include <hip/hip_runtime.h>
#include <hip/hip_bf16.h>
#include <math.h>

typedef __attribute__((ext_vector_type(8))) short short8;
typedef __attribute__((ext_vector_type(4))) float f32x4;

#define NB 4
#define NS 2048
#define ND 1024
#define NH 16
#define NDK 64
#define NF 4096
#define NM (NB*NS)   // 8192 rows total

// 1/sqrt(DK) * log2(e): scores come out of QK^T already in log2 domain
#define QSCALE 0.18033688f

__device__ __forceinline__ unsigned short f2b(float f) {
  union { __hip_bfloat16 h; unsigned short u; } c;
  c.h = __float2bfloat16(f);
  return c.u;
}

__device__ __forceinline__ void gload_lds16(const void* g, void* l) {
  __builtin_amdgcn_global_load_lds((const __attribute__((address_space(1))) void*)g,
                                   (__attribute__((address_space(3))) void*)l,
                                   16, 0, 0);
}

// ---------------- conversions / weight prep ----------------

__global__ __launch_bounds__(256)
void cvt_f32_bf16(const float* __restrict__ in, unsigned short* __restrict__ out, int n4) {
  int i = blockIdx.x * 256 + threadIdx.x;
  if (i >= n4) return;
  float4 v = ((const float4*)in)[i];
  ushort4 o;
  o.x = f2b(v.x); o.y = f2b(v.y); o.z = f2b(v.z); o.w = f2b(v.w);
  ((ushort4*)out)[i] = o;
}

// src: fp32 [K][N] (row stride ldsrc); dst: bf16 [N][K] (row stride lddst)
__global__ __launch_bounds__(256)
void transpose_generic(const float* __restrict__ src, unsigned short* __restrict__ dst,
                       int ldsrc, int lddst) {
  __shared__ float t[32][33];
  int k0 = blockIdx.x * 32, n0 = blockIdx.y * 32;
  int tx = threadIdx.x, ty = threadIdx.y;
  for (int r = ty; r < 32; r += 8)
    t[r][tx] = src[(size_t)(k0 + r) * ldsrc + n0 + tx];
  __syncthreads();
  for (int r = ty; r < 32; r += 8)
    dst[(size_t)(n0 + r) * lddst + k0 + tx] = f2b(t[tx][r]);
}

// Wq/Wk/Wv: [H, D, DK] fp32  ->  Wqkvt: bf16 [3072][1024]
// Q block pre-scaled by 1/sqrt(DK)*log2e
__global__ __launch_bounds__(256)
void transpose_qkv(const float* __restrict__ Wq, const float* __restrict__ Wk,
                   const float* __restrict__ Wv, unsigned short* __restrict__ dst) {
  int z = blockIdx.z, which = z / 16, h = z % 16;
  const float* src = (which == 0 ? Wq : which == 1 ? Wk : Wv) + (size_t)h * ND * NDK;
  float scale = (which == 0) ? QSCALE : 1.0f;
  unsigned short* d = dst + (size_t)(which * 1024 + h * 64) * ND;
  __shared__ float t[32][33];
  int k0 = blockIdx.x * 32, n0 = blockIdx.y * 32;
  int tx = threadIdx.x, ty = threadIdx.y;
  for (int r = ty; r < 32; r += 8)
    t[r][tx] = src[(size_t)(k0 + r) * NDK + n0 + tx];
  __syncthreads();
  for (int r = ty; r < 32; r += 8)
    d[(size_t)(n0 + r) * ND + k0 + tx] = f2b(t[tx][r] * scale);
}

__global__ __launch_bounds__(256)
void pack_bias(const float* __restrict__ bq, const float* __restrict__ bk,
               const float* __restrict__ bv, float* __restrict__ out) {
  int i = blockIdx.x * 256 + threadIdx.x;
  if (i >= 3072) return;
  float v = (i < 1024) ? bq[i] * QSCALE : (i < 2048 ? bk[i - 1024] : bv[i - 2048]);
  out[i] = v;
}

// V transpose: qkv [8192][3072] (v at col 2048+h*64) -> vt [64 bh][64 d][2048 s]
__global__ __launch_bounds__(256)
void transpose_v(const unsigned short* __restrict__ qkv, unsigned short* __restrict__ vt) {
  __shared__ unsigned short t[32][33];
  int bh = blockIdx.z; int b = bh >> 4, h = bh & 15;
  int s0 = blockIdx.x * 32;
  int d0 = blockIdx.y * 32;
  int tx = threadIdx.x, ty = threadIdx.y;
  for (int r = ty; r < 32; r += 8)
    t[r][tx] = qkv[(size_t)(b * NS + s0 + r) * 3072 + 2048 + h * 64 + d0 + tx];
  __syncthreads();
  for (int r = ty; r < 32; r += 8)
    vt[((size_t)bh * 64 + d0 + r) * NS + s0 + tx] = t[tx][r];
}

// ---------------- GEMM: C = A(bf16 [M][K]) @ Bt(bf16 [N][K])^T + bias ----------------

template<int EPI>
__global__ __launch_bounds__(256)
void gemm_bt(const unsigned short* __restrict__ A, const unsigned short* __restrict__ Bt,
             const float* __restrict__ bias, void* __restrict__ Cout,
             int M, int N, int K)
{
  __shared__ __align__(16) unsigned short As[128 * 32];
  __shared__ __align__(16) unsigned short Bs[128 * 32];
  const int n0 = blockIdx.x * 128;
  const int m0 = blockIdx.y * 128;
  const int tid = threadIdx.x;
  const int wave = tid >> 6, lane = tid & 63;
  const int l16 = lane & 15, lhi = lane >> 4;
  const int wr = wave >> 1, wc = wave & 1;
  const int ca = wave * 2;
  const int srow = lane >> 2;
  const int skp = (lane & 3) * 8;

  f32x4 acc[4][4] = {};

  for (int k0 = 0; k0 < K; k0 += 32) {
    __syncthreads();
#pragma unroll
    for (int c = ca; c < ca + 2; ++c)
      gload_lds16(A + (size_t)(m0 + c * 16 + srow) * K + (k0 + skp), &As[c * 512]);
#pragma unroll
    for (int c = ca; c < ca + 2; ++c)
      gload_lds16(Bt + (size_t)(n0 + c * 16 + srow) * K + (k0 + skp), &Bs[c * 512]);
    __syncthreads();

    short8 af[4], bf[4];
#pragma unroll
    for (int i = 0; i < 4; ++i)
      af[i] = *(const short8*)&As[(wr * 64 + i * 16 + l16) * 32 + lhi * 8];
#pragma unroll
    for (int j = 0; j < 4; ++j)
      bf[j] = *(const short8*)&Bs[(wc * 64 + j * 16 + l16) * 32 + lhi * 8];
#pragma unroll
    for (int i = 0; i < 4; ++i)
#pragma unroll
      for (int j = 0; j < 4; ++j)
        acc[i][j] = __builtin_amdgcn_mfma_f32_16x16x32_bf16(af[i], bf[j], acc[i][j], 0, 0, 0);
  }

#pragma unroll
  for (int i = 0; i < 4; ++i) {
    const int row = m0 + wr * 64 + i * 16 + lhi * 4;
#pragma unroll
    for (int j = 0; j < 4; ++j) {
      const int col = n0 + wc * 64 + j * 16 + l16;
      const float bv = bias[col];
#pragma unroll
      for (int r = 0; r < 4; ++r) {
        float v = acc[i][j][r] + bv;
        size_t idx = (size_t)(row + r) * N + col;
        if (EPI == 0)      ((unsigned short*)Cout)[idx] = f2b(v);
        else if (EPI == 1) ((float*)Cout)[idx] = v;
        else               ((unsigned short*)Cout)[idx] = f2b(tanhf(v));
      }
    }
  }
}

// ---------------- flash attention (swapped QK^T, in-lane softmax) ----------------
// qkv: bf16 [8192][3072] (q pre-scaled to log2 domain); vtg: bf16 [64][64][2048]
// ctx: bf16 [8192][1024]. 1D grid of 2048 blocks (XCD-swizzled), 4 waves x 16 q-rows.

__global__ __launch_bounds__(256)
void attn_fwd(const unsigned short* __restrict__ qkv, const unsigned short* __restrict__ vtg,
              unsigned short* __restrict__ ctx)
{
  // bijective XCD swizzle: 2048 blocks = 8 XCDs x 256
  const int id = blockIdx.x;
  const int swz = (id & 7) * 256 + (id >> 3);
  const int qt = swz & 31;
  const int bh = swz >> 5;
  const int b = bh >> 4, h = bh & 15;
  const int row0 = b * NS + qt * 64;
  const int tid = threadIdx.x;
  const int wave = tid >> 6, lane = tid & 63;
  const int l16 = lane & 15, lhi = lane >> 4;

  __shared__ __align__(16) unsigned short Ks[2][64 * 64];
  __shared__ __align__(16) unsigned short Vs[2][64 * 64];   // [d][key], swizzled
  __shared__ __align__(16) unsigned short Ps[4][16 * 64];   // wave-private, swizzled

  const unsigned short* kbase = qkv + ND + (size_t)h * 64;      // + row*3072
  const unsigned short* vbase = vtg + (size_t)bh * 64 * NS;     // + d*NS + key

  // staging: chunk c in [0,512): row=c>>3, swizzled slot sb=(c&7)*16 bytes
  // inverse swizzle on global source: featByte = sb ^ ((row&7)<<4)
  const int c0 = tid, c1 = 256 + tid;
  const int r0 = c0 >> 3, r1 = c1 >> 3;
  const int f0 = ((((c0 & 7) << 4) ^ ((r0 & 7) << 4)) >> 1);   // element offset in row
  const int f1 = ((((c1 & 7) << 4) ^ ((r1 & 7) << 4)) >> 1);
  const int ldsb0 = wave * 512;          // element base for inst 0 (chunk = wave*64 + lane)
  const int ldsb1 = 2048 + wave * 512;   // element base for inst 1

  // Q fragments (rows = this wave's 16 q-rows; used as B-operand after swap)
  short8 qf[2];
  {
    const unsigned short* qrow = qkv + (size_t)(row0 + wave * 16 + l16) * 3072 + h * 64;
    qf[0] = *(const short8*)(qrow + lhi * 8);
    qf[1] = *(const short8*)(qrow + 32 + lhi * 8);
  }

  f32x4 o[4] = {};
  float mr = -INFINITY;   // running max for q = l16 (log2 domain)
  float lr = 0.f;         // per-lane PARTIAL sum for q = l16 (this lhi-slice of keys)

  auto STAGE = [&](int buf, int kt) {
    const size_t kr = (size_t)(b * NS + kt * 64);
    const int kb64 = kt * 64;
    gload_lds16(kbase + (kr + r0) * 3072 + f0, &Ks[buf][ldsb0]);
    gload_lds16(kbase + (kr + r1) * 3072 + f1, &Ks[buf][ldsb1]);
    gload_lds16(vbase + (size_t)r0 * NS + kb64 + f0, &Vs[buf][ldsb0]);
    gload_lds16(vbase + (size_t)r1 * NS + kb64 + f1, &Vs[buf][ldsb1]);
  };

  auto COMPUTE = [&](int buf) {
    const char* kb = (const char*)&Ks[buf][0];
    const char* vb = (const char*)&Vs[buf][0];
    char* pb = (char*)&Ps[wave][0];

    // S^T = K @ Q^T (log2 domain): lane holds S[key=j*16+lhi*4+r][q=l16]
    // (kf/qf loads identical to unswapped; only operand order differs)
    f32x4 s[4] = {};
    __builtin_amdgcn_s_setprio(1);
#pragma unroll
    for (int c = 0; c < 2; ++c)
#pragma unroll
      for (int j = 0; j < 4; ++j) {
        const int row = j * 16 + l16;
        short8 kf = *(const short8*)(kb + row * 128 + ((c * 64 + lhi * 16) ^ ((row & 7) << 4)));
        s[j] = __builtin_amdgcn_mfma_f32_16x16x32_bf16(kf, qf[c], s[j], 0, 0, 0);
      }
    __builtin_amdgcn_s_setprio(0);

    // in-lane max over this lane's 16 keys, then 2-step cross-lhi reduce
    float mx = s[0][0];
#pragma unroll
    for (int j = 0; j < 4; ++j)
#pragma unroll
      for (int r = 0; r < 4; ++r) mx = fmaxf(mx, s[j][r]);
    mx = fmaxf(mx, __shfl_xor(mx, 16));
    mx = fmaxf(mx, __shfl_xor(mx, 32));

    // defer-max (T13, THR=8 in log2 domain): rescale only on real growth
    if (__any(mx > mr + 8.f)) {
      const float nm = fmaxf(mr, mx);
      const float al = __builtin_amdgcn_exp2f(mr - nm);
      mr = nm;
      lr *= al;
      float alq[4];
#pragma unroll
      for (int r = 0; r < 4; ++r) alq[r] = __shfl(al, lhi * 4 + r);
#pragma unroll
      for (int j = 0; j < 4; ++j)
#pragma unroll
        for (int r = 0; r < 4; ++r) o[j][r] *= alq[r];
    }

    // P = exp2(S - m), per-lane partial row-sum (no cross-lane reduce here)
    float ls = 0.f;
#pragma unroll
    for (int j = 0; j < 4; ++j)
#pragma unroll
      for (int r = 0; r < 4; ++r) {
        float t = __builtin_amdgcn_exp2f(s[j][r] - mr);
        s[j][r] = t; ls += t;
      }
    lr += ls;

    // P -> LDS: Ps[q=l16][key=j*16+lhi*4+{0..3}], packed pairs, swizzled
#pragma unroll
    for (int j = 0; j < 4; ++j)
#pragma unroll
      for (int rr = 0; rr < 2; ++rr) {
        unsigned int w = (unsigned int)f2b(s[j][2 * rr]) | ((unsigned int)f2b(s[j][2 * rr + 1]) << 16);
        *(unsigned int*)(pb + l16 * 128 + ((j * 32 + lhi * 8 + rr * 4) ^ ((l16 & 7) << 4))) = w;
      }

    // O += P @ V
    __builtin_amdgcn_s_setprio(1);
#pragma unroll
    for (int c = 0; c < 2; ++c) {
      short8 pf = *(const short8*)(pb + l16 * 128 + ((c * 64 + lhi * 16) ^ ((l16 & 7) << 4)));
#pragma unroll
      for (int j = 0; j < 4; ++j) {
        const int row = j * 16 + l16;
        short8 vf = *(const short8*)(vb + row * 128 + ((c * 64 + lhi * 16) ^ ((row & 7) << 4)));
        o[j] = __builtin_amdgcn_mfma_f32_16x16x32_bf16(pf, vf, o[j], 0, 0, 0);
      }
    }
    __builtin_amdgcn_s_setprio(0);
  };

  STAGE(0, 0);
  __syncthreads();
  int cur = 0;
  for (int kt = 0; kt < NS / 64 - 1; ++kt) {
    STAGE(cur ^ 1, kt + 1);
    COMPUTE(cur);
    __syncthreads();
    cur ^= 1;
  }
  COMPUTE(cur);

  // finalize row sums: butterfly over lhi groups, then broadcast to o-rows
  float t = lr;
  t += __shfl_xor(t, 16);
  t += __shfl_xor(t, 32);
  float rinv[4];
#pragma unroll
  for (int r = 0; r < 4; ++r) rinv[r] = 1.0f / __shfl(t, lhi * 4 + r);
#pragma unroll
  for (int j = 0; j < 4; ++j)
#pragma unroll
    for (int r = 0; r < 4; ++r) {
      const int row = row0 + wave * 16 + lhi * 4 + r;
      ctx[(size_t)row * ND + h * 64 + j * 16 + l16] = f2b(o[j][r] * rinv[r]);
    }
}

// ---------------- fused residual + LayerNorm ----------------

template<int WB>
__global__ __launch_bounds__(256)
void ln_fused(const float* xa, const float* xb,
              const float* g, const float* beta,
              float* of, unsigned short* ob)
{
  const int row = blockIdx.x;
  const int tid = threadIdx.x;
  const int wave = tid >> 6, lane = tid & 63;
  __shared__ float r1[4], r2[4];
  float4 a = ((const float4*)(xa + (size_t)row * ND))[tid];
  float4 b = ((const float4*)(xb + (size_t)row * ND))[tid];
  float v0 = a.x + b.x, v1 = a.y + b.y, v2 = a.z + b.z, v3 = a.w + b.w;
  float sm = v0 + v1 + v2 + v3;
#pragma unroll
  for (int d = 1; d < 64; d <<= 1) sm += __shfl_xor(sm, d);
  if (lane == 0) r1[wave] = sm;
  __syncthreads();
  const float mu = (r1[0] + r1[1] + r1[2] + r1[3]) * (1.0f / ND);
  const float d0 = v0 - mu, d1 = v1 - mu, d2 = v2 - mu, d3 = v3 - mu;
  float vs = d0 * d0 + d1 * d1 + d2 * d2 + d3 * d3;
#pragma unroll
  for (int d = 1; d < 64; d <<= 1) vs += __shfl_xor(vs, d);
  if (lane == 0) r2[wave] = vs;
  __syncthreads();
  const float var = (r2[0] + r2[1] + r2[2] + r2[3]) * (1.0f / ND);
  const float inv = rsqrtf(var + 1e-5f);
  float4 gg = ((const float4*)g)[tid];
  float4 bb = ((const float4*)beta)[tid];
  float o0 = d0 * inv * gg.x + bb.x;
  float o1 = d1 * inv * gg.y + bb.y;
  float o2 = d2 * inv * gg.z + bb.z;
  float o3 = d3 * inv * gg.w + bb.w;
  float4 ov; ov.x = o0; ov.y = o1; ov.z = o2; ov.w = o3;
  ((float4*)(of + (size_t)row * ND))[tid] = ov;
  if (WB) {
    ushort4 w; w.x = f2b(o0); w.y = f2b(o1); w.z = f2b(o2); w.w = f2b(o3);
    ((ushort4*)(ob + (size_t)row * ND))[tid] = w;
  }
}

// ---------------- launch ----------------

extern "C" void kernel_launch(void* const* d_in, const int* in_sizes, int n_in,
                              void* d_out, int out_size, void* d_ws, size_t ws_size,
                              hipStream_t stream)
{
  (void)in_sizes; (void)n_in; (void)out_size; (void)ws_size;
  const float* x   = (const float*)d_in[0];
  const float* Wq  = (const float*)d_in[1];
  const float* bq  = (const float*)d_in[2];
  const float* Wk  = (const float*)d_in[3];
  const float* bk  = (const float*)d_in[4];
  const float* Wv  = (const float*)d_in[5];
  const float* bv  = (const float*)d_in[6];
  const float* Wo  = (const float*)d_in[7];
  const float* bo  = (const float*)d_in[8];
  const float* g1  = (const float*)d_in[9];
  const float* be1 = (const float*)d_in[10];
  const float* W1  = (const float*)d_in[11];
  const float* b1  = (const float*)d_in[12];
  const float* W2  = (const float*)d_in[13];
  const float* b2  = (const float*)d_in[14];
  const float* g2  = (const float*)d_in[15];
  const float* be2 = (const float*)d_in[16];

  char* ws = (char*)d_ws;
  const size_t MB = 1ull << 20;
  unsigned short* x_bf  = (unsigned short*)(ws);             // 16 MiB, dead after G1
  unsigned short* vtg   = (unsigned short*)(ws);             // 16 MiB, overlays x_bf (after G1)
  unsigned short* qkv   = (unsigned short*)(ws + 16 * MB);   // 48 MiB, dead after attn
  unsigned short* ff1   = (unsigned short*)(ws);             // 64 MiB, overlays vtg+qkv
  unsigned short* ctx   = (unsigned short*)(ws + 64 * MB);   // 16 MiB, dead after G2
  unsigned short* h_bf  = (unsigned short*)(ws + 64 * MB);   // 16 MiB, overlays ctx
  unsigned short* Wqkvt = (unsigned short*)(ws + 80 * MB);   // 6 MiB
  unsigned short* Wot   = (unsigned short*)(ws + 86 * MB);   // 2 MiB
  unsigned short* W1t   = (unsigned short*)(ws + 88 * MB);   // 8 MiB
  unsigned short* W2t   = (unsigned short*)(ws + 96 * MB);   // 8 MiB
  float*          bqkv  = (float*)(ws + 104 * MB);           // 12 KiB
  float*          h_f   = (float*)(ws + 105 * MB);           // 32 MiB
  float*          gout  = (float*)d_out;                     // 32 MiB fp32 scratch

  cvt_f32_bf16<<<NM * ND / 4 / 256, 256, 0, stream>>>(x, x_bf, NM * ND / 4);
  transpose_qkv<<<dim3(32, 2, 48), dim3(32, 8), 0, stream>>>(Wq, Wk, Wv, Wqkvt);
  transpose_generic<<<dim3(32, 32), dim3(32, 8), 0, stream>>>(Wo, Wot, 1024, 1024);
  transpose_generic<<<dim3(32, 128), dim3(32, 8), 0, stream>>>(W1, W1t, 4096, 1024);
  transpose_generic<<<dim3(128, 32), dim3(32, 8), 0, stream>>>(W2, W2t, 1024, 4096);
  pack_bias<<<12, 256, 0, stream>>>(bq, bk, bv, bqkv);

  // QKV projection (q pre-scaled into log2 domain)
  gemm_bt<0><<<dim3(3072 / 128, NM / 128), 256, 0, stream>>>(x_bf, Wqkvt, bqkv, qkv, NM, 3072, 1024);
  // V transpose (x_bf now dead; vtg overlays it)
  transpose_v<<<dim3(64, 2, 64), dim3(32, 8), 0, stream>>>(qkv, vtg);
  // attention
  attn_fwd<<<2048, 256, 0, stream>>>(qkv, vtg, ctx);
  // output projection -> fp32 (into d_out scratch)
  gemm_bt<1><<<dim3(1024 / 128, NM / 128), 256, 0, stream>>>(ctx, Wot, bo, gout, NM, 1024, 1024);
  // h = LN(x + attn_out)
  ln_fused<1><<<NM, 256, 0, stream>>>(x, gout, g1, be1, h_f, h_bf);
  // FFN1 with tanh
  gemm_bt<2><<<dim3(4096 / 128, NM / 128), 256, 0, stream>>>(h_bf, W1t, b1, ff1, NM, 4096, 1024);
  // FFN2 -> fp32 (d_out scratch)
  gemm_bt<1><<<dim3(1024 / 128, NM / 128), 256, 0, stream>>>(ff1, W2t, b2, gout, NM, 1024, 4096);
  // out = LN(h + ff)
  ln_fused<0><<<NM, 256, 0, stream>>>(h_f, gout, g2, be2, (float*)d_out, nullptr);
}